// Round 6
// baseline (333.105 us; speedup 1.0000x reference)
//
#include <hip/hip_runtime.h>

// ---------- types ----------
typedef __attribute__((ext_vector_type(8))) short bfrag8;   // 8 bf16 bit patterns (4 VGPRs)
typedef __attribute__((ext_vector_type(4))) short bfrag4;
typedef __attribute__((ext_vector_type(4))) float f32x4;

#if defined(__has_builtin)
#if __has_builtin(__builtin_amdgcn_cvt_pk_bf16_f32)
#define HAVE_PK_BF16 1
#endif
#endif

// ---------- bf16 helpers ----------
__device__ __forceinline__ float bf2f(unsigned short h){
  unsigned u = ((unsigned)h) << 16;
  return __builtin_bit_cast(float, u);
}
__device__ __forceinline__ unsigned short f2bf(float f){
  unsigned u = __builtin_bit_cast(unsigned, f);
  u = u + 0x7FFFu + ((u >> 16) & 1u);        // round-to-nearest-even
  return (unsigned short)(u >> 16);
}
// pack two f32 -> two bf16 in one dword (lo=a, hi=b); single instr on gfx950
__device__ __forceinline__ unsigned pk2bf(float a, float b){
#ifdef HAVE_PK_BF16
  typedef __attribute__((ext_vector_type(2))) __bf16 bf16x2_t;
  bf16x2_t r = __builtin_amdgcn_cvt_pk_bf16_f32(a, b);
  return __builtin_bit_cast(unsigned, r);
#else
  return (unsigned)f2bf(a) | ((unsigned)f2bf(b) << 16);
#endif
}
__device__ __forceinline__ bfrag8 gload8(const unsigned short* p){ // 16B-aligned global, bf16
  int4 v = *(const int4*)p;
  return __builtin_bit_cast(bfrag8, v);
}
__device__ __forceinline__ bfrag8 lds_load8(const unsigned short* p){ // 8B-aligned LDS
  bfrag4 lo = *(const bfrag4*)p;
  bfrag4 hi = *(const bfrag4*)(p + 4);
  bfrag8 r;
#pragma unroll
  for (int j = 0; j < 4; j++){ r[j] = lo[j]; r[4+j] = hi[j]; }
  return r;
}
__device__ __forceinline__ bfrag8 lds_load16B(const unsigned short* p){ // 16B-aligned LDS -> ds_read_b128
  int4 v = *(const int4*)p;
  return __builtin_bit_cast(bfrag8, v);
}
__device__ __forceinline__ f32x4 mfma16(bfrag8 a, bfrag8 b, f32x4 c){
  return __builtin_amdgcn_mfma_f32_16x16x32_bf16(a, b, c, 0, 0, 0);
}

// bf16 select from packed int4 kv word: t in [0,4) compile-time after unroll.
// k lives in .x/.y, v lives in .z/.w ; this helper is for the v half.
__device__ __forceinline__ float bfv(int4 v, int t){
  unsigned w = (t < 2) ? (unsigned)v.z : (unsigned)v.w;
  unsigned h = (t & 1) ? (w >> 16) : (w & 0xFFFFu);
  return bf2f((unsigned short)h);
}
__device__ __forceinline__ float bfk(int4 v, int t){
  unsigned w = (t < 2) ? (unsigned)v.x : (unsigned)v.y;
  unsigned h = (t & 1) ? (w >> 16) : (w & 0xFFFFu);
  return bf2f((unsigned short)h);
}
__device__ __forceinline__ float bfq(uint2 v, int t){
  unsigned w = (t < 2) ? v.x : v.y;
  unsigned h = (t & 1) ? (w >> 16) : (w & 0xFFFFu);
  return bf2f((unsigned short)h);
}

// ---------- dtype-dispatched accessors (flag: 1 = tensor is f32) ----------
__device__ __forceinline__ float ldf(const void* p, size_t i, int f32){
  return f32 ? ((const float*)p)[i] : bf2f(((const unsigned short*)p)[i]);
}
__device__ __forceinline__ unsigned short ldbf(const void* p, size_t i, int f32){
  return f32 ? f2bf(((const float*)p)[i]) : ((const unsigned short*)p)[i];
}
__device__ __forceinline__ bfrag8 load8bf(const void* p, size_t base, int f32){
  if (f32){
    const float* f = (const float*)p + base;
    float4 x = *(const float4*)f;
    float4 y = *(const float4*)(f + 4);
    bfrag8 r;
    r[0]=(short)f2bf(x.x); r[1]=(short)f2bf(x.y); r[2]=(short)f2bf(x.z); r[3]=(short)f2bf(x.w);
    r[4]=(short)f2bf(y.x); r[5]=(short)f2bf(y.y); r[6]=(short)f2bf(y.z); r[7]=(short)f2bf(y.w);
    return r;
  }
  return gload8((const unsigned short*)p + base);
}

// ---------- reductions ----------
template<int CTRL>
__device__ __forceinline__ float dpp_add(float x){
  int xi = __builtin_bit_cast(int, x);
  int yi = __builtin_amdgcn_update_dpp(0, xi, CTRL, 0xF, 0xF, true);
  return x + __builtin_bit_cast(float, yi);
}
__device__ __forceinline__ float row16_sum(float x){
  x = dpp_add<0xB1>(x);    // quad_perm [1,0,3,2]  : + lane^1
  x = dpp_add<0x4E>(x);    // quad_perm [2,3,0,1]  : + lane^2
  x = dpp_add<0x141>(x);   // row_half_mirror      : + other quad
  x = dpp_add<0x140>(x);   // row_mirror           : + other 8-group
  return x;
}
__device__ __forceinline__ float xgrp_sum(float x){
  x += __shfl_xor(x, 16, 64);
  x += __shfl_xor(x, 32, 64);
  return x;
}
__device__ __forceinline__ int wave_isum(int x){
#pragma unroll
  for (int s = 1; s < 64; s <<= 1) x += __shfl_xor(x, s, 64);
  return x;
}

// ============================================================================
// Kernel 0a: dtype sniffing — parallel, one wave per tensor.
// ============================================================================
struct Ptrs { const void* p[21]; int n[21]; };
struct PrepPtrs { const void* w[6]; const void* wp; const void* b[11]; };

__global__ void detect_kernel(Ptrs ptrs, int* flags){
  const int lane = threadIdx.x & 63;
  const int wid = blockIdx.x * 4 + (threadIdx.x >> 6);
  if (wid >= 21) return;
  if (wid == 2){ if (lane == 0) flags[2] = 0; return; }   // neighbor_idx is int32

  const unsigned short* p = (const unsigned short*)ptrs.p[wid];
  int m = ptrs.n[wid]; if (m > 128) m = 128;
  int insane = 0, evenZero = 0, evenCnt = 0, oddNZ = 0, oddCnt = 0;
#pragma unroll
  for (int s = 0; s < 2; s++){
    int i = lane + s*64;
    if (i < m){
      unsigned short h = p[i];
      int e = (h >> 7) & 0xFF;
      bool z = (h & 0x7FFF) == 0;
      if (!z && (e == 0xFF || e < 90 || e > 140)) insane++;
      if (i & 1){ oddCnt++;  if (!z) oddNZ++; }
      else      { evenCnt++; if (z)  evenZero++; }
    }
  }
  insane = wave_isum(insane);
  evenZero = wave_isum(evenZero); evenCnt = wave_isum(evenCnt);
  oddNZ = wave_isum(oddNZ);       oddCnt = wave_isum(oddCnt);
  if (lane == 0){
    int f = 0;
    if (insane > 0) f = 1;
    else if (evenZero * 4 >= evenCnt * 3 && oddNZ * 4 >= oddCnt * 3) f = 1;
    flags[wid] = f;
  }
}

// ============================================================================
// Kernel 0b: canonicalize params. Weights -> fragment-ordered bf16.
// ============================================================================
__global__ void prep_kernel(PrepPtrs pp, const int* __restrict__ flags,
                            unsigned short* __restrict__ wfrag,
                            unsigned short* __restrict__ wp_bf,
                            float* __restrict__ biases)
{
  const int gid = blockIdx.x * 256 + threadIdx.x;
  const int gstride = gridDim.x * 256;
  const int wflag[6] = {3,5,7,13,17,19};          // wq,wk,wv,wg1,wg2,wo
  for (int idx = gid; idx < 6*4096; idx += gstride){
    int m = idx >> 12;
    int r = idx & 4095;          // ((ks*4+t)*64 + lane)*8 + j
    int j = r & 7;
    int lane = (r >> 3) & 63;
    int kt = r >> 9;
    int ks = kt >> 2, t = kt & 3;
    int o = lane >> 4, rl = lane & 15;
    int src = (ks*32 + o*8 + j)*64 + t*16 + rl;   // B[k][n] fragment element
    wfrag[idx] = ldbf(pp.w[m], src, flags[wflag[m]]);
  }
  if (blockIdx.x == 0){
    for (int i = threadIdx.x; i < 192; i += 256) wp_bf[i] = ldbf(pp.wp, i, flags[9]);
    const int bflag[11] = {4,6,8,10,11,12,14,15,16,18,20};
    for (int i = threadIdx.x; i < 11*64; i += 256){
      int m = i >> 6;
      biases[i] = ldf(pp.b[m], i & 63, flags[bflag[m]]);
    }
  }
}

// ============================================================================
// Kernel 1: q,k,v = features @ {wq,wk,wv} + bias -> bf16 scratch.
// q_ws: swizzled rows of 64 shorts: (row, c) at row*64 + 4*(c&15) + (c>>4).
// kv_ws (v3): k and v INTERLEAVED per row of 128 shorts: for each rl in [0,16):
//   [rl*8 + 0..3] = k channels {rl, rl+16, rl+32, rl+48}
//   [rl*8 + 4..7] = v channels {rl, rl+16, rl+32, rl+48}
// so pt_kernel's neighbor gather is ONE dwordx4 per lane (k+v fused).
// ============================================================================
__global__ __launch_bounds__(256, 2)
void qkv_kernel(const void* __restrict__ feat,
                const unsigned short* __restrict__ wfrag,
                const float* __restrict__ biases,
                unsigned short* __restrict__ q_ws, unsigned short* __restrict__ kv_ws,
                const int* __restrict__ flags, int N)
{
  const int F_feat = flags[1];
  const int lane = threadIdx.x & 63;
  const int wave = threadIdx.x >> 6;
  const int o = lane >> 4, rl = lane & 15;

  bfrag8 wqf[2][4], wkf[2][4], wvf[2][4];
#pragma unroll
  for (int ks = 0; ks < 2; ks++)
#pragma unroll
    for (int t = 0; t < 4; t++){
      int off = ((ks*4 + t)*64 + lane)*8;
      wqf[ks][t] = gload8(wfrag + off);
      wkf[ks][t] = gload8(wfrag + 4096 + off);
      wvf[ks][t] = gload8(wfrag + 8192 + off);
    }
  float bqC[4], bkC[4], bvC[4];
#pragma unroll
  for (int t = 0; t < 4; t++){
    bqC[t] = biases[0*64 + t*16 + rl];
    bkC[t] = biases[1*64 + t*16 + rl];
    bvC[t] = biases[2*64 + t*16 + rl];
  }

  const int ntiles = (N + 15) >> 4;
  for (int tile = blockIdx.x*4 + wave; tile < ntiles; tile += gridDim.x*4){
    const int n0 = tile * 16;
    int ar = n0 + rl; if (ar >= N) ar = N - 1;
    bfrag8 a[2];
#pragma unroll
    for (int ks = 0; ks < 2; ks++) a[ks] = load8bf(feat, (size_t)ar*64 + ks*32 + o*8, F_feat);

    f32x4 zq[4], zk[4], zv[4];
#pragma unroll
    for (int t = 0; t < 4; t++){
      f32x4 aq = {0.f,0.f,0.f,0.f}, ak = {0.f,0.f,0.f,0.f}, av = {0.f,0.f,0.f,0.f};
#pragma unroll
      for (int ks = 0; ks < 2; ks++){
        aq = mfma16(a[ks], wqf[ks][t], aq);
        ak = mfma16(a[ks], wkf[ks][t], ak);
        av = mfma16(a[ks], wvf[ks][t], av);
      }
      zq[t] = aq; zk[t] = ak; zv[t] = av;
    }
#pragma unroll
    for (int q = 0; q < 4; q++){
      size_t row = n0 + o*4 + q;
      if ((int)row < N){
        uint2 uq;
        uq.x = pk2bf(zq[0][q]+bqC[0], zq[1][q]+bqC[1]);
        uq.y = pk2bf(zq[2][q]+bqC[2], zq[3][q]+bqC[3]);
        *(uint2*)(q_ws + row*64 + 4*rl) = uq;
        uint4 kv;
        kv.x = pk2bf(zk[0][q]+bkC[0], zk[1][q]+bkC[1]);
        kv.y = pk2bf(zk[2][q]+bkC[2], zk[3][q]+bkC[3]);
        kv.z = pk2bf(zv[0][q]+bvC[0], zv[1][q]+bvC[1]);
        kv.w = pk2bf(zv[2][q]+bvC[2], zv[3][q]+bvC[3]);
        *(uint4*)(kv_ws + row*128 + 8*rl) = kv;
      }
    }
  }
}

// ============================================================================
// Kernel 2: fused point-transformer. 256-thread blocks, one wave per point.
//
// v3 (latency fix — v2 counters: MfmaUtil 5.4%, VALU 39%, HBM 48%, 522 MB
// traffic/dispatch => gather-latency-bound):
//  * k+v fused into one kv row -> ONE dwordx4 gather per neighbor per lane.
//  * software pipeline: neighbor INDICES two iterations ahead, gather DATA
//    (kv rows, q, residual, points) one iteration ahead. Miss latency hides
//    under the previous iteration's MFMA/LN compute.
//  * gathered kv stays PACKED (int4) until use (attn_in / softmax) — keeps
//    live VGPR ~110 (v2 measured 84), no spill.
//  * grid 1024 = 4 blocks/CU exactly resident; ~12 iters/wave amortizes
//    the pipeline prologue.
//  * non-temporal out store (write-once, drops RFO fetch).
// ============================================================================
__global__ __launch_bounds__(256, 3)
void pt_kernel(const void* __restrict__ points,
               const void* __restrict__ feat,
               const int* __restrict__ nidx,
               const unsigned short* __restrict__ q_ws,
               const unsigned short* __restrict__ kv_ws,
               const unsigned short* __restrict__ wfrag,
               const unsigned short* __restrict__ wp_bf,
               const float* __restrict__ biases,
               const int* __restrict__ flags, void* __restrict__ out, int N)
{
  __shared__ unsigned short xbuf[4][16][68];   // per-wave C<->A bounce (stride 68)
  __shared__ unsigned short ybuf[4][64];
  __shared__ __align__(16) unsigned short wlds[3*4096]; // wg1 | wg2 | wo fragments

  const int F_pts = flags[0], F_feat = flags[1];
  const int lane = threadIdx.x & 63;
  const int wave = threadIdx.x >> 6;
  const int o = lane >> 4, rl = lane & 15;

  // ---- stage wg1/wg2/wo fragments into LDS (once per block) ----
  {
    const unsigned short* wsrc = wfrag + 3*4096;
    for (int i = threadIdx.x*8; i < 3*4096; i += 256*8)
      *(int4*)(wlds + i) = *(const int4*)(wsrc + i);
  }
  __syncthreads();

  // ---- per-wave constants ----
  bfrag8 wpf[4];
#pragma unroll
  for (int t = 0; t < 4; t++){
    bfrag8 a = {0,0,0,0,0,0,0,0};
    if (o == 0){
#pragma unroll
      for (int j = 0; j < 3; j++) a[j] = (short)wp_bf[j*64 + t*16 + rl];
    }
    wpf[t] = a;
  }
  float bpC[4], gpC[4], bePC[4], bg1C[4], ggC[4], beGC[4], bg2C[4], boC[4];
#pragma unroll
  for (int t = 0; t < 4; t++){
    int c = t*16 + rl;
    bpC[t]  = biases[3*64 + c];  gpC[t]  = biases[4*64 + c];  bePC[t] = biases[5*64 + c];
    bg1C[t] = biases[6*64 + c];  ggC[t]  = biases[7*64 + c];  beGC[t] = biases[8*64 + c];
    bg2C[t] = biases[9*64 + c];  boC[t]  = biases[10*64 + c];
  }

  const unsigned short* wldsL = wlds + lane*8;   // per-lane base; rest is imm offsets

  const int wstride = gridDim.x * 4;
  const int n_first = blockIdx.x*4 + wave;

  // ---- software pipeline state ----
  int4  kv_c[4];                 // current point's 4 neighbor kv rows (packed bf16)
  uint2 q_c = {0,0};
  float res_c = 0.f;
  float pj_c0=0.f, pj_c1=0.f, pj_c2=0.f;   // points[jr] (A-layout neighbor, per-rl)
  float pn_c0=0.f, pn_c1=0.f, pn_c2=0.f;   // points[n]
  int   jr_n = 0, jq_n0=0, jq_n1=0, jq_n2=0, jq_n3=0;  // indices for n+wstride
#pragma unroll
  for (int q = 0; q < 4; q++){ kv_c[q].x=0; kv_c[q].y=0; kv_c[q].z=0; kv_c[q].w=0; }

  // prologue: idx(n0) -> data(n0); idx(n1)
  {
    const int n0 = n_first;
    if (n0 < N){
      int jr0 = nidx[n0*16 + rl];
      int jt0 = nidx[n0*16 + o*4 + 0];
      int jt1 = nidx[n0*16 + o*4 + 1];
      int jt2 = nidx[n0*16 + o*4 + 2];
      int jt3 = nidx[n0*16 + o*4 + 3];
      kv_c[0] = *(const int4*)(kv_ws + (size_t)jt0*128 + 8*rl);
      kv_c[1] = *(const int4*)(kv_ws + (size_t)jt1*128 + 8*rl);
      kv_c[2] = *(const int4*)(kv_ws + (size_t)jt2*128 + 8*rl);
      kv_c[3] = *(const int4*)(kv_ws + (size_t)jt3*128 + 8*rl);
      q_c = *(const uint2*)(q_ws + (size_t)n0*64 + 4*rl);
      res_c = ldf(feat, (size_t)n0*64 + lane, F_feat);
      pj_c0 = ldf(points, (size_t)jr0*3 + 0, F_pts);
      pj_c1 = ldf(points, (size_t)jr0*3 + 1, F_pts);
      pj_c2 = ldf(points, (size_t)jr0*3 + 2, F_pts);
      pn_c0 = ldf(points, (size_t)n0*3 + 0, F_pts);
      pn_c1 = ldf(points, (size_t)n0*3 + 1, F_pts);
      pn_c2 = ldf(points, (size_t)n0*3 + 2, F_pts);
    }
    const int n1 = n_first + wstride;
    if (n1 < N){
      jr_n  = nidx[n1*16 + rl];
      jq_n0 = nidx[n1*16 + o*4 + 0];
      jq_n1 = nidx[n1*16 + o*4 + 1];
      jq_n2 = nidx[n1*16 + o*4 + 2];
      jq_n3 = nidx[n1*16 + o*4 + 3];
    }
  }

  for (int n = n_first; n < N; n += wstride){
    // ---- issue NEXT iteration's gathers first (hide miss latency under compute)
    const int n_nxt = n + wstride;
    int4  kv_x[4]; uint2 q_x = {0,0}; float res_x = 0.f;
    float pj_x0=0.f, pj_x1=0.f, pj_x2=0.f, pn_x0=0.f, pn_x1=0.f, pn_x2=0.f;
#pragma unroll
    for (int q = 0; q < 4; q++){ kv_x[q].x=0; kv_x[q].y=0; kv_x[q].z=0; kv_x[q].w=0; }
    if (n_nxt < N){
      kv_x[0] = *(const int4*)(kv_ws + (size_t)jq_n0*128 + 8*rl);
      kv_x[1] = *(const int4*)(kv_ws + (size_t)jq_n1*128 + 8*rl);
      kv_x[2] = *(const int4*)(kv_ws + (size_t)jq_n2*128 + 8*rl);
      kv_x[3] = *(const int4*)(kv_ws + (size_t)jq_n3*128 + 8*rl);
      q_x = *(const uint2*)(q_ws + (size_t)n_nxt*64 + 4*rl);
      res_x = ldf(feat, (size_t)n_nxt*64 + lane, F_feat);
      pj_x0 = ldf(points, (size_t)jr_n*3 + 0, F_pts);
      pj_x1 = ldf(points, (size_t)jr_n*3 + 1, F_pts);
      pj_x2 = ldf(points, (size_t)jr_n*3 + 2, F_pts);
      pn_x0 = ldf(points, (size_t)n_nxt*3 + 0, F_pts);
      pn_x1 = ldf(points, (size_t)n_nxt*3 + 1, F_pts);
      pn_x2 = ldf(points, (size_t)n_nxt*3 + 2, F_pts);
    }
    // ---- refill index pipeline (for n + 2*wstride)
    const int n_n2 = n + 2*wstride;
    if (n_n2 < N){
      jr_n  = nidx[n_n2*16 + rl];
      jq_n0 = nidx[n_n2*16 + o*4 + 0];
      jq_n1 = nidx[n_n2*16 + o*4 + 1];
      jq_n2 = nidx[n_n2*16 + o*4 + 2];
      jq_n3 = nidx[n_n2*16 + o*4 + 3];
    }

    // ---- p = relu(LN(rel @ wp + bp)) via MFMA (K padded 3->32) ----
    float rel0 = pj_c0 - pn_c0, rel1 = pj_c1 - pn_c1, rel2 = pj_c2 - pn_c2;
    bfrag8 ap = {0,0,0,0,0,0,0,0};
    if (o == 0){
      ap[0] = (short)f2bf(rel0); ap[1] = (short)f2bf(rel1); ap[2] = (short)f2bf(rel2);
    }
    f32x4 pacc[4];
#pragma unroll
    for (int t = 0; t < 4; t++){
      f32x4 z = {0.f,0.f,0.f,0.f};
      pacc[t] = mfma16(ap, wpf[t], z);
    }
    float p_val[4][4];                        // [t][q], C-layout
#pragma unroll
    for (int q = 0; q < 4; q++){
      float xv[4]; float s = 0.f, s2 = 0.f;
#pragma unroll
      for (int t = 0; t < 4; t++){ xv[t] = pacc[t][q] + bpC[t]; s += xv[t]; s2 += xv[t]*xv[t]; }
      s = row16_sum(s); s2 = row16_sum(s2);
      float mu = s * (1.f/64.f);
      float var = s2 * (1.f/64.f) - mu*mu;
      float rs = rsqrtf(var + 1e-5f);
#pragma unroll
      for (int t = 0; t < 4; t++){
        float a = rs * gpC[t];
        p_val[t][q] = fmaxf(xv[t]*a + (bePC[t] - mu*a), 0.f);
      }
    }

    // ---- attn_in = q - gk + p in C-layout; bounce C->A (paired bf16 pack) ----
#pragma unroll
    for (int q = 0; q < 4; q++){
      float a0 = bfq(q_c,0) - bfk(kv_c[q],0) + p_val[0][q];
      float a1 = bfq(q_c,1) - bfk(kv_c[q],1) + p_val[1][q];
      float a2 = bfq(q_c,2) - bfk(kv_c[q],2) + p_val[2][q];
      float a3 = bfq(q_c,3) - bfk(kv_c[q],3) + p_val[3][q];
      unsigned u01 = pk2bf(a0, a1), u23 = pk2bf(a2, a3);
      int r = o*4 + q;
      xbuf[wave][r][0*16 + rl] = (unsigned short)u01;
      xbuf[wave][r][1*16 + rl] = (unsigned short)(u01 >> 16);
      xbuf[wave][r][2*16 + rl] = (unsigned short)u23;
      xbuf[wave][r][3*16 + rl] = (unsigned short)(u23 >> 16);
    }
    f32x4 hacc[4] = {{0.f,0.f,0.f,0.f},{0.f,0.f,0.f,0.f},{0.f,0.f,0.f,0.f},{0.f,0.f,0.f,0.f}};
#pragma unroll
    for (int ks = 0; ks < 2; ks++){
      bfrag8 af = lds_load8(&xbuf[wave][rl][ks*32 + o*8]);
#pragma unroll
      for (int t = 0; t < 4; t++){
        bfrag8 wf = lds_load16B(wldsL + (ks*4 + t)*512);           // wg1 frag
        hacc[t] = mfma16(af, wf, hacc[t]);
      }
    }

    // ---- LN + relu -> h; bounce C->A; GEMM2 ----
#pragma unroll
    for (int q = 0; q < 4; q++){
      float xv[4]; float s = 0.f, s2 = 0.f;
#pragma unroll
      for (int t = 0; t < 4; t++){ xv[t] = hacc[t][q] + bg1C[t]; s += xv[t]; s2 += xv[t]*xv[t]; }
      s = row16_sum(s); s2 = row16_sum(s2);
      float mu = s * (1.f/64.f);
      float var = s2 * (1.f/64.f) - mu*mu;
      float rs = rsqrtf(var + 1e-5f);
      float h0,h1,h2,h3;
      {
        float a = rs * ggC[0]; h0 = fmaxf(xv[0]*a + (beGC[0] - mu*a), 0.f);
        a = rs * ggC[1];       h1 = fmaxf(xv[1]*a + (beGC[1] - mu*a), 0.f);
        a = rs * ggC[2];       h2 = fmaxf(xv[2]*a + (beGC[2] - mu*a), 0.f);
        a = rs * ggC[3];       h3 = fmaxf(xv[3]*a + (beGC[3] - mu*a), 0.f);
      }
      unsigned u01 = pk2bf(h0, h1);
      unsigned u23 = pk2bf(h2, h3);
      int r = o*4 + q;
      // note: overwrites xbuf AFTER attn A-frags were consumed above
      xbuf[wave][r][0*16 + rl] = (unsigned short)u01;
      xbuf[wave][r][1*16 + rl] = (unsigned short)(u01 >> 16);
      xbuf[wave][r][2*16 + rl] = (unsigned short)u23;
      xbuf[wave][r][3*16 + rl] = (unsigned short)(u23 >> 16);
    }
    f32x4 wacc[4] = {{0.f,0.f,0.f,0.f},{0.f,0.f,0.f,0.f},{0.f,0.f,0.f,0.f},{0.f,0.f,0.f,0.f}};
#pragma unroll
    for (int ks = 0; ks < 2; ks++){
      bfrag8 hf = lds_load8(&xbuf[wave][rl][ks*32 + o*8]);
#pragma unroll
      for (int t = 0; t < 4; t++){
        bfrag8 wf = lds_load16B(wldsL + 4096 + (ks*4 + t)*512);    // wg2 frag
        wacc[t] = mfma16(hf, wf, wacc[t]);
      }
    }

    // ---- softmax over neighbors (no max-shift: |w| << 88, f32 exp safe) ----
    float y[4];
#pragma unroll
    for (int t = 0; t < 4; t++){
      float se = 0.f, z = 0.f;
#pragma unroll
      for (int q = 0; q < 4; q++){
        float e = __expf(wacc[t][q] + bg2C[t]);
        se += e;
        z  += e * (bfv(kv_c[q], t) + p_val[t][q]);
      }
      se = xgrp_sum(se); z = xgrp_sum(z);
      y[t] = z * __builtin_amdgcn_rcpf(se);
    }

    // ---- out = y @ wo + bo + residual ----
    if (o == 0){
      unsigned u01 = pk2bf(y[0], y[1]), u23 = pk2bf(y[2], y[3]);
      ybuf[wave][0*16 + rl] = (unsigned short)u01;
      ybuf[wave][1*16 + rl] = (unsigned short)(u01 >> 16);
      ybuf[wave][2*16 + rl] = (unsigned short)u23;
      ybuf[wave][3*16 + rl] = (unsigned short)(u23 >> 16);
    }
    f32x4 oacc[4] = {{0.f,0.f,0.f,0.f},{0.f,0.f,0.f,0.f},{0.f,0.f,0.f,0.f},{0.f,0.f,0.f,0.f}};
#pragma unroll
    for (int ks = 0; ks < 2; ks++){
      bfrag8 yf = lds_load8(&ybuf[wave][ks*32 + o*8]);
#pragma unroll
      for (int t = 0; t < 4; t++){
        bfrag8 wf = lds_load16B(wldsL + 2*4096 + (ks*4 + t)*512);  // wo frag
        oacc[t] = mfma16(yf, wf, oacc[t]);
      }
    }

    float ov = 0.f;
#pragma unroll
    for (int t = 0; t < 4; t++) if (o == t) ov = oacc[t][0] + boC[t];
    float outv = ov + res_c;
    if (F_feat) __builtin_nontemporal_store(outv, (float*)out + (size_t)n*64 + lane);
    else        __builtin_nontemporal_store(f2bf(outv), (unsigned short*)out + (size_t)n*64 + lane);

    // ---- rotate pipeline ----
#pragma unroll
    for (int q = 0; q < 4; q++) kv_c[q] = kv_x[q];
    q_c = q_x; res_c = res_x;
    pj_c0 = pj_x0; pj_c1 = pj_x1; pj_c2 = pj_x2;
    pn_c0 = pn_x0; pn_c1 = pn_x1; pn_c2 = pn_x2;
  }
}

// ============================================================================
extern "C" void kernel_launch(void* const* d_in, const int* in_sizes, int n_in,
                              void* d_out, int out_size, void* d_ws, size_t ws_size,
                              hipStream_t stream)
{
  const int N = in_sizes[1] / 64;

  unsigned short* q_ws  = (unsigned short*)d_ws;           // N*64 shorts
  unsigned short* kv_ws = q_ws + (size_t)N * 64;           // N*128 shorts (k|v interleaved)
  char* base = (char*)d_ws + (size_t)3 * N * 64 * sizeof(unsigned short);
  int*            flags  = (int*)base;                            // 128 B
  unsigned short* wfrag  = (unsigned short*)(base + 256);         // 49152 B
  unsigned short* wp_bf  = (unsigned short*)(base + 256 + 49152); // 384 B (pad 512)
  float*          biases = (float*)(base + 256 + 49152 + 512);    // 2816 B

  Ptrs ptrs;
  for (int i = 0; i < 21; i++){ ptrs.p[i] = d_in[i]; ptrs.n[i] = in_sizes[i]; }
  PrepPtrs pp;
  pp.w[0] = d_in[3];  pp.w[1] = d_in[5];  pp.w[2] = d_in[7];
  pp.w[3] = d_in[13]; pp.w[4] = d_in[17]; pp.w[5] = d_in[19];
  pp.wp = d_in[9];
  pp.b[0] = d_in[4];  pp.b[1] = d_in[6];  pp.b[2] = d_in[8];  pp.b[3] = d_in[10];
  pp.b[4] = d_in[11]; pp.b[5] = d_in[12]; pp.b[6] = d_in[14]; pp.b[7] = d_in[15];
  pp.b[8] = d_in[16]; pp.b[9] = d_in[18]; pp.b[10] = d_in[20];

  detect_kernel<<<6, 256, 0, stream>>>(ptrs, flags);
  prep_kernel<<<32, 256, 0, stream>>>(pp, flags, wfrag, wp_bf, biases);
  qkv_kernel<<<512, 256, 0, stream>>>(d_in[1], wfrag, biases, q_ws, kv_ws, flags, N);
  pt_kernel<<<1024, 256, 0, stream>>>(d_in[0], d_in[1], (const int*)d_in[2], q_ws, kv_ws,
                                      wfrag, wp_bf, biases, flags, d_out, N);
}

// Round 8
// 264.586 us; speedup vs baseline: 1.2590x; 1.2590x over previous
//
#include <hip/hip_runtime.h>

// ---------- types ----------
typedef __attribute__((ext_vector_type(8))) short bfrag8;   // 8 bf16 bit patterns (4 VGPRs)
typedef __attribute__((ext_vector_type(4))) short bfrag4;
typedef __attribute__((ext_vector_type(4))) float f32x4;

#if defined(__has_builtin)
#if __has_builtin(__builtin_amdgcn_cvt_pk_bf16_f32)
#define HAVE_PK_BF16 1
#endif
#endif

// ---------- bf16 helpers ----------
__device__ __forceinline__ float bf2f(unsigned short h){
  unsigned u = ((unsigned)h) << 16;
  return __builtin_bit_cast(float, u);
}
__device__ __forceinline__ unsigned short f2bf(float f){
  unsigned u = __builtin_bit_cast(unsigned, f);
  u = u + 0x7FFFu + ((u >> 16) & 1u);        // round-to-nearest-even
  return (unsigned short)(u >> 16);
}
// pack two f32 -> two bf16 in one dword (lo=a, hi=b); single instr on gfx950
__device__ __forceinline__ unsigned pk2bf(float a, float b){
#ifdef HAVE_PK_BF16
  typedef __attribute__((ext_vector_type(2))) __bf16 bf16x2_t;
  bf16x2_t r = __builtin_amdgcn_cvt_pk_bf16_f32(a, b);
  return __builtin_bit_cast(unsigned, r);
#else
  return (unsigned)f2bf(a) | ((unsigned)f2bf(b) << 16);
#endif
}
__device__ __forceinline__ bfrag8 gload8(const unsigned short* p){ // 16B-aligned global, bf16
  int4 v = *(const int4*)p;
  return __builtin_bit_cast(bfrag8, v);
}
__device__ __forceinline__ bfrag8 lds_load8(const unsigned short* p){ // 8B-aligned LDS
  bfrag4 lo = *(const bfrag4*)p;
  bfrag4 hi = *(const bfrag4*)(p + 4);
  bfrag8 r;
#pragma unroll
  for (int j = 0; j < 4; j++){ r[j] = lo[j]; r[4+j] = hi[j]; }
  return r;
}
__device__ __forceinline__ bfrag8 lds_load16B(const unsigned short* p){ // 16B-aligned LDS -> ds_read_b128
  int4 v = *(const int4*)p;
  return __builtin_bit_cast(bfrag8, v);
}
__device__ __forceinline__ f32x4 mfma16(bfrag8 a, bfrag8 b, f32x4 c){
  return __builtin_amdgcn_mfma_f32_16x16x32_bf16(a, b, c, 0, 0, 0);
}

// bf16 select from packed kv word (compile-time t after unroll).
// k lives in .x/.y, v lives in .z/.w of the int4.
__device__ __forceinline__ float bfk(int4 v, int t){
  unsigned w = (t < 2) ? (unsigned)v.x : (unsigned)v.y;
  unsigned h = (t & 1) ? (w >> 16) : (w & 0xFFFFu);
  return bf2f((unsigned short)h);
}
__device__ __forceinline__ float bfv(int4 v, int t){
  unsigned w = (t < 2) ? (unsigned)v.z : (unsigned)v.w;
  unsigned h = (t & 1) ? (w >> 16) : (w & 0xFFFFu);
  return bf2f((unsigned short)h);
}
__device__ __forceinline__ float bfq(uint2 v, int t){
  unsigned w = (t < 2) ? v.x : v.y;
  unsigned h = (t & 1) ? (w >> 16) : (w & 0xFFFFu);
  return bf2f((unsigned short)h);
}

// ---------- dtype-dispatched accessors (flag: 1 = tensor is f32) ----------
__device__ __forceinline__ float ldf(const void* p, size_t i, int f32){
  return f32 ? ((const float*)p)[i] : bf2f(((const unsigned short*)p)[i]);
}
__device__ __forceinline__ unsigned short ldbf(const void* p, size_t i, int f32){
  return f32 ? f2bf(((const float*)p)[i]) : ((const unsigned short*)p)[i];
}
__device__ __forceinline__ bfrag8 load8bf(const void* p, size_t base, int f32){
  if (f32){
    const float* f = (const float*)p + base;
    float4 x = *(const float4*)f;
    float4 y = *(const float4*)(f + 4);
    bfrag8 r;
    r[0]=(short)f2bf(x.x); r[1]=(short)f2bf(x.y); r[2]=(short)f2bf(x.z); r[3]=(short)f2bf(x.w);
    r[4]=(short)f2bf(y.x); r[5]=(short)f2bf(y.y); r[6]=(short)f2bf(y.z); r[7]=(short)f2bf(y.w);
    return r;
  }
  return gload8((const unsigned short*)p + base);
}

// ---------- reductions ----------
template<int CTRL>
__device__ __forceinline__ float dpp_add(float x){
  int xi = __builtin_bit_cast(int, x);
  int yi = __builtin_amdgcn_update_dpp(0, xi, CTRL, 0xF, 0xF, true);
  return x + __builtin_bit_cast(float, yi);
}
__device__ __forceinline__ float row16_sum(float x){
  x = dpp_add<0xB1>(x);    // quad_perm [1,0,3,2]  : + lane^1
  x = dpp_add<0x4E>(x);    // quad_perm [2,3,0,1]  : + lane^2
  x = dpp_add<0x141>(x);   // row_half_mirror      : + other quad
  x = dpp_add<0x140>(x);   // row_mirror           : + other 8-group
  return x;
}
__device__ __forceinline__ float xgrp_sum(float x){
  x += __shfl_xor(x, 16, 64);
  x += __shfl_xor(x, 32, 64);
  return x;
}
__device__ __forceinline__ int wave_isum(int x){
#pragma unroll
  for (int s = 1; s < 64; s <<= 1) x += __shfl_xor(x, s, 64);
  return x;
}

// ============================================================================
// Kernel 0a: dtype sniffing — parallel, one wave per tensor.
// ============================================================================
struct Ptrs { const void* p[21]; int n[21]; };
struct PrepPtrs { const void* w[6]; const void* wp; const void* b[11]; };

__global__ void detect_kernel(Ptrs ptrs, int* flags){
  const int lane = threadIdx.x & 63;
  const int wid = blockIdx.x * 4 + (threadIdx.x >> 6);
  if (wid >= 21) return;
  if (wid == 2){ if (lane == 0) flags[2] = 0; return; }   // neighbor_idx is int32

  const unsigned short* p = (const unsigned short*)ptrs.p[wid];
  int m = ptrs.n[wid]; if (m > 128) m = 128;
  int insane = 0, evenZero = 0, evenCnt = 0, oddNZ = 0, oddCnt = 0;
#pragma unroll
  for (int s = 0; s < 2; s++){
    int i = lane + s*64;
    if (i < m){
      unsigned short h = p[i];
      int e = (h >> 7) & 0xFF;
      bool z = (h & 0x7FFF) == 0;
      if (!z && (e == 0xFF || e < 90 || e > 140)) insane++;
      if (i & 1){ oddCnt++;  if (!z) oddNZ++; }
      else      { evenCnt++; if (z)  evenZero++; }
    }
  }
  insane = wave_isum(insane);
  evenZero = wave_isum(evenZero); evenCnt = wave_isum(evenCnt);
  oddNZ = wave_isum(oddNZ);       oddCnt = wave_isum(oddCnt);
  if (lane == 0){
    int f = 0;
    if (insane > 0) f = 1;
    else if (evenZero * 4 >= evenCnt * 3 && oddNZ * 4 >= oddCnt * 3) f = 1;
    flags[wid] = f;
  }
}

// ============================================================================
// Kernel 0b: canonicalize params. Weights -> fragment-ordered bf16.
// ============================================================================
__global__ void prep_kernel(PrepPtrs pp, const int* __restrict__ flags,
                            unsigned short* __restrict__ wfrag,
                            unsigned short* __restrict__ wp_bf,
                            float* __restrict__ biases)
{
  const int gid = blockIdx.x * 256 + threadIdx.x;
  const int gstride = gridDim.x * 256;
  const int wflag[6] = {3,5,7,13,17,19};          // wq,wk,wv,wg1,wg2,wo
  for (int idx = gid; idx < 6*4096; idx += gstride){
    int m = idx >> 12;
    int r = idx & 4095;          // ((ks*4+t)*64 + lane)*8 + j
    int j = r & 7;
    int lane = (r >> 3) & 63;
    int kt = r >> 9;
    int ks = kt >> 2, t = kt & 3;
    int o = lane >> 4, rl = lane & 15;
    int src = (ks*32 + o*8 + j)*64 + t*16 + rl;   // B[k][n] fragment element
    wfrag[idx] = ldbf(pp.w[m], src, flags[wflag[m]]);
  }
  if (blockIdx.x == 0){
    for (int i = threadIdx.x; i < 192; i += 256) wp_bf[i] = ldbf(pp.wp, i, flags[9]);
    const int bflag[11] = {4,6,8,10,11,12,14,15,16,18,20};
    for (int i = threadIdx.x; i < 11*64; i += 256){
      int m = i >> 6;
      biases[i] = ldf(pp.b[m], i & 63, flags[bflag[m]]);
    }
  }
}

// ============================================================================
// Kernel 1: q,k,v = features @ {wq,wk,wv} + bias -> bf16 scratch.
// q_ws: swizzled rows of 64 shorts: (row, c) at row*64 + 4*(c&15) + (c>>4).
// kv_ws: k and v INTERLEAVED per row of 128 shorts: for each rl in [0,16):
//   [rl*8 + 0..3] = k channels {rl, rl+16, rl+32, rl+48}
//   [rl*8 + 4..7] = v channels {rl, rl+16, rl+32, rl+48}
// so pt_kernel's neighbor gather is ONE dwordx4 per lane (k+v fused).
// ============================================================================
__global__ __launch_bounds__(256, 2)
void qkv_kernel(const void* __restrict__ feat,
                const unsigned short* __restrict__ wfrag,
                const float* __restrict__ biases,
                unsigned short* __restrict__ q_ws, unsigned short* __restrict__ kv_ws,
                const int* __restrict__ flags, int N)
{
  const int F_feat = flags[1];
  const int lane = threadIdx.x & 63;
  const int wave = threadIdx.x >> 6;
  const int o = lane >> 4, rl = lane & 15;

  bfrag8 wqf[2][4], wkf[2][4], wvf[2][4];
#pragma unroll
  for (int ks = 0; ks < 2; ks++)
#pragma unroll
    for (int t = 0; t < 4; t++){
      int off = ((ks*4 + t)*64 + lane)*8;
      wqf[ks][t] = gload8(wfrag + off);
      wkf[ks][t] = gload8(wfrag + 4096 + off);
      wvf[ks][t] = gload8(wfrag + 8192 + off);
    }
  float bqC[4], bkC[4], bvC[4];
#pragma unroll
  for (int t = 0; t < 4; t++){
    bqC[t] = biases[0*64 + t*16 + rl];
    bkC[t] = biases[1*64 + t*16 + rl];
    bvC[t] = biases[2*64 + t*16 + rl];
  }

  const int ntiles = (N + 15) >> 4;
  for (int tile = blockIdx.x*4 + wave; tile < ntiles; tile += gridDim.x*4){
    const int n0 = tile * 16;
    int ar = n0 + rl; if (ar >= N) ar = N - 1;
    bfrag8 a[2];
#pragma unroll
    for (int ks = 0; ks < 2; ks++) a[ks] = load8bf(feat, (size_t)ar*64 + ks*32 + o*8, F_feat);

    f32x4 zq[4], zk[4], zv[4];
#pragma unroll
    for (int t = 0; t < 4; t++){
      f32x4 aq = {0.f,0.f,0.f,0.f}, ak = {0.f,0.f,0.f,0.f}, av = {0.f,0.f,0.f,0.f};
#pragma unroll
      for (int ks = 0; ks < 2; ks++){
        aq = mfma16(a[ks], wqf[ks][t], aq);
        ak = mfma16(a[ks], wkf[ks][t], ak);
        av = mfma16(a[ks], wvf[ks][t], av);
      }
      zq[t] = aq; zk[t] = ak; zv[t] = av;
    }
#pragma unroll
    for (int q = 0; q < 4; q++){
      size_t row = n0 + o*4 + q;
      if ((int)row < N){
        uint2 uq;
        uq.x = pk2bf(zq[0][q]+bqC[0], zq[1][q]+bqC[1]);
        uq.y = pk2bf(zq[2][q]+bqC[2], zq[3][q]+bqC[3]);
        *(uint2*)(q_ws + row*64 + 4*rl) = uq;
        uint4 kv;
        kv.x = pk2bf(zk[0][q]+bkC[0], zk[1][q]+bkC[1]);
        kv.y = pk2bf(zk[2][q]+bkC[2], zk[3][q]+bkC[3]);
        kv.z = pk2bf(zv[0][q]+bvC[0], zv[1][q]+bvC[1]);
        kv.w = pk2bf(zv[2][q]+bvC[2], zv[3][q]+bvC[3]);
        *(uint4*)(kv_ws + row*128 + 8*rl) = kv;
      }
    }
  }
}

// ============================================================================
// Kernel 2: fused point-transformer. 256-thread blocks, one wave per point.
//
// v4 = v2 ordering + v3's two wins. POST-MORTEM of v3 (242µs vs v2's 172):
//   explicit rotate-pipeline was DEFEATED by the compiler — VGPR stayed 84,
//   proving the prefetch loads were sunk to the rotation point => burst of
//   gathers + vmcnt(0) at the iteration boundary, zero overlap. v2's layout
//   (gathers at TOP of iteration, first use in attn_in AFTER the independent
//   p-LN chain) is the working pipeline: the compiler cannot sink loads past
//   their first use, so the p-MFMA/DPP work (~no kv dependency) hides the
//   miss latency. KEEP: kv fused row (4 dwordx4 instead of 8 8B-loads),
//   non-temporal out stores (WRITE 110->79 MB). Grid back to 2048 (two
//   resident generations, backfill smooths the tail).
// ============================================================================
__global__ __launch_bounds__(256, 3)
void pt_kernel(const void* __restrict__ points,
               const void* __restrict__ feat,
               const int* __restrict__ nidx,
               const unsigned short* __restrict__ q_ws,
               const unsigned short* __restrict__ kv_ws,
               const unsigned short* __restrict__ wfrag,
               const unsigned short* __restrict__ wp_bf,
               const float* __restrict__ biases,
               const int* __restrict__ flags, void* __restrict__ out, int N)
{
  __shared__ unsigned short xbuf[4][16][68];   // per-wave C<->A bounce (stride 68)
  __shared__ unsigned short ybuf[4][64];
  __shared__ __align__(16) unsigned short wlds[3*4096]; // wg1 | wg2 | wo fragments

  const int F_pts = flags[0], F_feat = flags[1];
  const int lane = threadIdx.x & 63;
  const int wave = threadIdx.x >> 6;
  const int o = lane >> 4, rl = lane & 15;

  // ---- stage wg1/wg2/wo fragments into LDS (once per block) ----
  {
    const unsigned short* wsrc = wfrag + 3*4096;
    for (int i = threadIdx.x*8; i < 3*4096; i += 256*8)
      *(int4*)(wlds + i) = *(const int4*)(wsrc + i);
  }
  __syncthreads();

  // ---- per-wave constants ----
  bfrag8 wpf[4];
#pragma unroll
  for (int t = 0; t < 4; t++){
    bfrag8 a = {0,0,0,0,0,0,0,0};
    if (o == 0){
#pragma unroll
      for (int j = 0; j < 3; j++) a[j] = (short)wp_bf[j*64 + t*16 + rl];
    }
    wpf[t] = a;
  }
  float bpC[4], gpC[4], bePC[4], bg1C[4], ggC[4], beGC[4], bg2C[4], boC[4];
#pragma unroll
  for (int t = 0; t < 4; t++){
    int c = t*16 + rl;
    bpC[t]  = biases[3*64 + c];  gpC[t]  = biases[4*64 + c];  bePC[t] = biases[5*64 + c];
    bg1C[t] = biases[6*64 + c];  ggC[t]  = biases[7*64 + c];  beGC[t] = biases[8*64 + c];
    bg2C[t] = biases[9*64 + c];  boC[t]  = biases[10*64 + c];
  }

  const unsigned short* wldsL = wlds + lane*8;   // per-lane base; rest is imm offsets

  const int wstride = gridDim.x * 4;
  const int n_first = blockIdx.x*4 + wave;

  // ---- index prefetch (one iteration ahead) ----
  int jr_c = 0, jq_c0 = 0, jq_c1 = 0, jq_c2 = 0, jq_c3 = 0;
  if (n_first < N){
    jr_c  = nidx[n_first*16 + rl];
    jq_c0 = nidx[n_first*16 + o*4 + 0];
    jq_c1 = nidx[n_first*16 + o*4 + 1];
    jq_c2 = nidx[n_first*16 + o*4 + 2];
    jq_c3 = nidx[n_first*16 + o*4 + 3];
  }

  for (int n = n_first; n < N; n += wstride){
    const int jr = jr_c;

    // ---- gathers for CURRENT point, issued at the TOP of the iteration.
    // First use (attn_in / softmax) is after the independent p-LN chain, so
    // the compiler keeps the loads here and the MFMA/DPP work hides latency.
    int4 kv0 = *(const int4*)(kv_ws + (size_t)jq_c0*128 + 8*rl);
    int4 kv1 = *(const int4*)(kv_ws + (size_t)jq_c1*128 + 8*rl);
    int4 kv2 = *(const int4*)(kv_ws + (size_t)jq_c2*128 + 8*rl);
    int4 kv3 = *(const int4*)(kv_ws + (size_t)jq_c3*128 + 8*rl);
    uint2 q_c = *(const uint2*)(q_ws + (size_t)n*64 + 4*rl);
    const float res = ldf(feat, (size_t)n*64 + lane, F_feat);
    float rel0 = ldf(points, (size_t)jr*3 + 0, F_pts) - ldf(points, (size_t)n*3 + 0, F_pts);
    float rel1 = ldf(points, (size_t)jr*3 + 1, F_pts) - ldf(points, (size_t)n*3 + 1, F_pts);
    float rel2 = ldf(points, (size_t)jr*3 + 2, F_pts) - ldf(points, (size_t)n*3 + 2, F_pts);

    // ---- prefetch next iteration's neighbor indices ----
    {
      const int nn = n + wstride;
      if (nn < N){
        jr_c  = nidx[nn*16 + rl];
        jq_c0 = nidx[nn*16 + o*4 + 0];
        jq_c1 = nidx[nn*16 + o*4 + 1];
        jq_c2 = nidx[nn*16 + o*4 + 2];
        jq_c3 = nidx[nn*16 + o*4 + 3];
      }
    }

    // ---- p = relu(LN(rel @ wp + bp)) via MFMA (K padded 3->32) ----
    bfrag8 ap = {0,0,0,0,0,0,0,0};
    if (o == 0){
      ap[0] = (short)f2bf(rel0); ap[1] = (short)f2bf(rel1); ap[2] = (short)f2bf(rel2);
    }
    f32x4 pacc[4];
#pragma unroll
    for (int t = 0; t < 4; t++){
      f32x4 z = {0.f,0.f,0.f,0.f};
      pacc[t] = mfma16(ap, wpf[t], z);
    }
    float p_val[4][4];                        // [t][q], C-layout
#pragma unroll
    for (int q = 0; q < 4; q++){
      float xv[4]; float s = 0.f, s2 = 0.f;
#pragma unroll
      for (int t = 0; t < 4; t++){ xv[t] = pacc[t][q] + bpC[t]; s += xv[t]; s2 += xv[t]*xv[t]; }
      s = row16_sum(s); s2 = row16_sum(s2);
      float mu = s * (1.f/64.f);
      float var = s2 * (1.f/64.f) - mu*mu;
      float rs = rsqrtf(var + 1e-5f);
#pragma unroll
      for (int t = 0; t < 4; t++){
        float a = rs * gpC[t];
        p_val[t][q] = fmaxf(xv[t]*a + (bePC[t] - mu*a), 0.f);
      }
    }

    // ---- attn_in = q - gk + p in C-layout; bounce C->A (paired bf16 pack) ----
#pragma unroll
    for (int q = 0; q < 4; q++){
      int4 kvq = (q==0) ? kv0 : (q==1) ? kv1 : (q==2) ? kv2 : kv3;
      float a0 = bfq(q_c,0) - bfk(kvq,0) + p_val[0][q];
      float a1 = bfq(q_c,1) - bfk(kvq,1) + p_val[1][q];
      float a2 = bfq(q_c,2) - bfk(kvq,2) + p_val[2][q];
      float a3 = bfq(q_c,3) - bfk(kvq,3) + p_val[3][q];
      unsigned u01 = pk2bf(a0, a1), u23 = pk2bf(a2, a3);
      int r = o*4 + q;
      xbuf[wave][r][0*16 + rl] = (unsigned short)u01;
      xbuf[wave][r][1*16 + rl] = (unsigned short)(u01 >> 16);
      xbuf[wave][r][2*16 + rl] = (unsigned short)u23;
      xbuf[wave][r][3*16 + rl] = (unsigned short)(u23 >> 16);
    }
    f32x4 hacc[4] = {{0.f,0.f,0.f,0.f},{0.f,0.f,0.f,0.f},{0.f,0.f,0.f,0.f},{0.f,0.f,0.f,0.f}};
#pragma unroll
    for (int ks = 0; ks < 2; ks++){
      bfrag8 af = lds_load8(&xbuf[wave][rl][ks*32 + o*8]);
#pragma unroll
      for (int t = 0; t < 4; t++){
        bfrag8 wf = lds_load16B(wldsL + (ks*4 + t)*512);           // wg1 frag
        hacc[t] = mfma16(af, wf, hacc[t]);
      }
    }

    // ---- LN + relu -> h; bounce C->A; GEMM2 ----
#pragma unroll
    for (int q = 0; q < 4; q++){
      float xv[4]; float s = 0.f, s2 = 0.f;
#pragma unroll
      for (int t = 0; t < 4; t++){ xv[t] = hacc[t][q] + bg1C[t]; s += xv[t]; s2 += xv[t]*xv[t]; }
      s = row16_sum(s); s2 = row16_sum(s2);
      float mu = s * (1.f/64.f);
      float var = s2 * (1.f/64.f) - mu*mu;
      float rs = rsqrtf(var + 1e-5f);
      float h0,h1,h2,h3;
      {
        float a = rs * ggC[0]; h0 = fmaxf(xv[0]*a + (beGC[0] - mu*a), 0.f);
        a = rs * ggC[1];       h1 = fmaxf(xv[1]*a + (beGC[1] - mu*a), 0.f);
        a = rs * ggC[2];       h2 = fmaxf(xv[2]*a + (beGC[2] - mu*a), 0.f);
        a = rs * ggC[3];       h3 = fmaxf(xv[3]*a + (beGC[3] - mu*a), 0.f);
      }
      unsigned u01 = pk2bf(h0, h1);
      unsigned u23 = pk2bf(h2, h3);
      int r = o*4 + q;
      // note: overwrites xbuf AFTER attn A-frags were consumed above
      xbuf[wave][r][0*16 + rl] = (unsigned short)u01;
      xbuf[wave][r][1*16 + rl] = (unsigned short)(u01 >> 16);
      xbuf[wave][r][2*16 + rl] = (unsigned short)u23;
      xbuf[wave][r][3*16 + rl] = (unsigned short)(u23 >> 16);
    }
    f32x4 wacc[4] = {{0.f,0.f,0.f,0.f},{0.f,0.f,0.f,0.f},{0.f,0.f,0.f,0.f},{0.f,0.f,0.f,0.f}};
#pragma unroll
    for (int ks = 0; ks < 2; ks++){
      bfrag8 hf = lds_load8(&xbuf[wave][rl][ks*32 + o*8]);
#pragma unroll
      for (int t = 0; t < 4; t++){
        bfrag8 wf = lds_load16B(wldsL + 4096 + (ks*4 + t)*512);    // wg2 frag
        wacc[t] = mfma16(hf, wf, wacc[t]);
      }
    }

    // ---- softmax over neighbors (no max-shift: |w| << 88, f32 exp safe) ----
    float y[4];
#pragma unroll
    for (int t = 0; t < 4; t++){
      float se = 0.f, z = 0.f;
#pragma unroll
      for (int q = 0; q < 4; q++){
        int4 kvq = (q==0) ? kv0 : (q==1) ? kv1 : (q==2) ? kv2 : kv3;
        float e = __expf(wacc[t][q] + bg2C[t]);
        se += e;
        z  += e * (bfv(kvq, t) + p_val[t][q]);
      }
      se = xgrp_sum(se); z = xgrp_sum(z);
      y[t] = z * __builtin_amdgcn_rcpf(se);
    }

    // ---- out = y @ wo + bo + residual ----
    if (o == 0){
      unsigned u01 = pk2bf(y[0], y[1]), u23 = pk2bf(y[2], y[3]);
      ybuf[wave][0*16 + rl] = (unsigned short)u01;
      ybuf[wave][1*16 + rl] = (unsigned short)(u01 >> 16);
      ybuf[wave][2*16 + rl] = (unsigned short)u23;
      ybuf[wave][3*16 + rl] = (unsigned short)(u23 >> 16);
    }
    f32x4 oacc[4] = {{0.f,0.f,0.f,0.f},{0.f,0.f,0.f,0.f},{0.f,0.f,0.f,0.f},{0.f,0.f,0.f,0.f}};
#pragma unroll
    for (int ks = 0; ks < 2; ks++){
      bfrag8 yf = lds_load8(&ybuf[wave][ks*32 + o*8]);
#pragma unroll
      for (int t = 0; t < 4; t++){
        bfrag8 wf = lds_load16B(wldsL + 2*4096 + (ks*4 + t)*512);  // wo frag
        oacc[t] = mfma16(yf, wf, oacc[t]);
      }
    }

    float ov = 0.f;
#pragma unroll
    for (int t = 0; t < 4; t++) if (o == t) ov = oacc[t][0] + boC[t];
    float outv = ov + res;
    if (F_feat) __builtin_nontemporal_store(outv, (float*)out + (size_t)n*64 + lane);
    else        __builtin_nontemporal_store(f2bf(outv), (unsigned short*)out + (size_t)n*64 + lane);
  }
}

// ============================================================================
extern "C" void kernel_launch(void* const* d_in, const int* in_sizes, int n_in,
                              void* d_out, int out_size, void* d_ws, size_t ws_size,
                              hipStream_t stream)
{
  const int N = in_sizes[1] / 64;

  unsigned short* q_ws  = (unsigned short*)d_ws;           // N*64 shorts
  unsigned short* kv_ws = q_ws + (size_t)N * 64;           // N*128 shorts (k|v interleaved)
  char* base = (char*)d_ws + (size_t)3 * N * 64 * sizeof(unsigned short);
  int*            flags  = (int*)base;                            // 128 B
  unsigned short* wfrag  = (unsigned short*)(base + 256);         // 49152 B
  unsigned short* wp_bf  = (unsigned short*)(base + 256 + 49152); // 384 B (pad 512)
  float*          biases = (float*)(base + 256 + 49152 + 512);    // 2816 B

  Ptrs ptrs;
  for (int i = 0; i < 21; i++){ ptrs.p[i] = d_in[i]; ptrs.n[i] = in_sizes[i]; }
  PrepPtrs pp;
  pp.w[0] = d_in[3];  pp.w[1] = d_in[5];  pp.w[2] = d_in[7];
  pp.w[3] = d_in[13]; pp.w[4] = d_in[17]; pp.w[5] = d_in[19];
  pp.wp = d_in[9];
  pp.b[0] = d_in[4];  pp.b[1] = d_in[6];  pp.b[2] = d_in[8];  pp.b[3] = d_in[10];
  pp.b[4] = d_in[11]; pp.b[5] = d_in[12]; pp.b[6] = d_in[14]; pp.b[7] = d_in[15];
  pp.b[8] = d_in[16]; pp.b[9] = d_in[18]; pp.b[10] = d_in[20];

  detect_kernel<<<6, 256, 0, stream>>>(ptrs, flags);
  prep_kernel<<<32, 256, 0, stream>>>(pp, flags, wfrag, wp_bf, biases);
  qkv_kernel<<<512, 256, 0, stream>>>(d_in[1], wfrag, biases, q_ws, kv_ws, flags, N);
  pt_kernel<<<2048, 256, 0, stream>>>(d_in[0], d_in[1], (const int*)d_in[2], q_ws, kv_ws,
                                      wfrag, wp_bf, biases, flags, d_out, N);
}